// Round 7
// baseline (148.715 us; speedup 1.0000x reference)
//
#include <hip/hip_runtime.h>
#include <stdint.h>

// Problem constants (fixed by reference)
#define NB 32    // batch
#define NC 64    // input channels
#define NH 64
#define NW 64
#define NO 512   // output channels
#define HP 66    // h-padded rows (1 zero row top+bottom)

typedef __bf16 bf16x8 __attribute__((ext_vector_type(8)));
typedef short  s16x8  __attribute__((ext_vector_type(8)));
typedef float  f32x4  __attribute__((ext_vector_type(4)));

__device__ __forceinline__ uint16_t f2bf(float f) {
  uint32_t u = __builtin_bit_cast(uint32_t, f);
  u += 0x7fffu + ((u >> 16) & 1u);   // round-to-nearest-even
  return (uint16_t)(u >> 16);
}

// async global->LDS, 16B per lane. LDS dest = wave-uniform base + lane*16.
__device__ __forceinline__ void gld16(const uint16_t* g, uint16_t* l) {
  __builtin_amdgcn_global_load_lds(
      (const __attribute__((address_space(1))) void*)(g),
      (__attribute__((address_space(3))) void*)(l), 16, 0, 0);
}

// ---------------- kernel 1: build effective weights (pre-swizzled) -------
// W_eff[o][c][p] = sum_s coef[o,s]*dict[idx[o,s]][c][p], p = kh*3+kw.
// Global layout matches the LDS tile EXACTLY (staging is a linear DMA):
//   Wl[((p*NO + o)*8 + ((c>>3) ^ (o&7)))*8 + (c&7)]
__global__ void k_build_w(const float* __restrict__ dict,
                          const float* __restrict__ coef,
                          const int*   __restrict__ idx,
                          uint16_t*    __restrict__ Wl) {
  __shared__ float tmp[576];
  const int o = blockIdx.x;
  const int t = threadIdx.x;      // 0..575
  float v = 0.f;
#pragma unroll
  for (int s = 0; s < 4; ++s)
    v += coef[o * 4 + s] * dict[idx[o * 4 + s] * 576 + t];
  tmp[t] = v;
  __syncthreads();
  const int c = t & 63, p = t >> 6;   // 576 = 9*64
  const int sl = ((p * NO + o) * 8 + ((c >> 3) ^ (o & 7))) * 8 + (c & 7);
  Wl[sl] = f2bf(tmp[c * 9 + p]);
}

// ---------------- kernel 2: x NCHW fp32 -> padded swizzled NHWC bf16 -----
// xh[b][hp][w][c] with hp in [0,66), rows 0 and 65 all-zero; within a row,
// 16B chunk (c>>3) stored at chunk position ((c>>3) ^ (w&7)).
__global__ void k_nhwc(const float* __restrict__ x, uint16_t* __restrict__ xh) {
  const int bh = blockIdx.x;            // b*66 + hp
  const int b = bh / HP, hp = bh % HP;
  const int t = threadIdx.x;            // 256
  uint16_t* row = xh + (size_t)(b * HP + hp) * 4096;
  if (hp == 0 || hp == HP - 1) {        // zero pad rows
    int4* r4 = reinterpret_cast<int4*>(row);
    r4[t]       = int4{0, 0, 0, 0};
    r4[t + 256] = int4{0, 0, 0, 0};
    return;
  }
  __shared__ float tile[64][65];
  const int h = hp - 1;
  const int w = t & 63;
#pragma unroll
  for (int c = (t >> 6); c < 64; c += 4)
    tile[c][w] = x[((size_t)(b * NC + c) * NH + h) * NW + w];
  __syncthreads();
#pragma unroll
  for (int i = 0; i < 2; ++i) {
    const int s = t + i * 256;          // 512 slots of 16B
    const int w2 = s >> 3, cb = s & 7;
    uint32_t d[4];
#pragma unroll
    for (int j = 0; j < 4; ++j) {
      const uint32_t lo = f2bf(tile[cb * 8 + 2 * j][w2]);
      const uint32_t hi = f2bf(tile[cb * 8 + 2 * j + 1][w2]);
      d[j] = lo | (hi << 16);
    }
    reinterpret_cast<int4*>(row)[w2 * 8 + (cb ^ (w2 & 7))] =
        int4{(int)d[0], (int)d[1], (int)d[2], (int)d[3]};
  }
}

// ---------------- kernel 3: persistent implicit-GEMM conv ----------------
// 256 blocks (1/CU), 512 thr (8 waves). Block owns one (b, h-octet):
// stages xs ONCE, then loops 4 o-tiles of 128.
// Per wave per o-tile: 128 pix x 64 o, acc[8][4] (D rows = PIXELS via
// operand swap -> lane holds 4 consecutive w -> direct f32x4 stores).
// Schedule: per (g,q,dh) fine phase {<=12 ds_reads; setprio1; 32 MFMA;
// setprio0; raw barrier}. A-restage between g-groups; at o-tile end the
// 6 restage gld16s are issued BEFORE the 32 stores so vmcnt(32) waits
// only the loads and stores drain under the next o-tile's compute.
__global__ __launch_bounds__(512, 2) void k_conv(
    const uint16_t* __restrict__ xh,   // [NB][66][64][64] bf16, pre-swizzled
    const uint16_t* __restrict__ Wl,   // [9][512][64] bf16, pre-swizzled
    const float*    __restrict__ bias,
    float*          __restrict__ out) {
  __shared__ __align__(16) uint16_t xs[10 * 66 * 64];     // 84.4 KB
  __shared__ __align__(16) uint16_t as[3 * 128 * 64];     // 48 KB

  const int t = threadIdx.x;
  const int blk = blockIdx.x;                 // 256 blocks
  // XCD-chunked: XCD k gets gy in [k*32,(k+1)*32) -> 4 b's per XCD L2
  const int gy = (blk & 7) * 32 + (blk >> 3);
  const int b  = gy >> 3;
  const int h0 = (gy & 7) * 8;

  const int lane = t & 63;
  const int wid  = t >> 6;      // 0..7

  // ---- zero the w-halo slots (slot 0 and 65 of each of 10 rows) ----
  if (t < 160) {
    const int r = t >> 4, sl = (t >> 3) & 1, j = t & 7;
    reinterpret_cast<int4*>(xs)[r * 528 + sl * 520 + j] = int4{0, 0, 0, 0};
  }

  // ---- stage x interior ONCE: rows 0..7 -> wave wid; rows 8,9 split ----
  {
    const uint16_t* srow = xh + (size_t)(b * HP + h0 + wid) * 4096;
    uint16_t* drow = xs + wid * 4224 + 64;     // skip w-halo slot 0
#pragma unroll
    for (int k = 0; k < 8; ++k)
      gld16(srow + k * 512 + lane * 8, drow + k * 512);
    const int r2 = 8 + (wid >> 2);
    const int kb = (wid & 3) * 2;
    const uint16_t* srow2 = xh + (size_t)(b * HP + h0 + r2) * 4096;
    uint16_t* drow2 = xs + r2 * 4224 + 64;
    gld16(srow2 + kb * 512 + lane * 8, drow2 + kb * 512);
    gld16(srow2 + (kb + 1) * 512 + lane * 8, drow2 + (kb + 1) * 512);
  }

  // ---- A-group staging: (ot, g) -> taps p = dh*3 + g, dh = 0..2 ----
  // 48 chunks of 1 KB; wave wid takes chunks wid*6 .. wid*6+5.
  auto stage_a = [&](int otp, int g) {
    const int oo = otp * 128;
#pragma unroll
    for (int j = 0; j < 6; ++j) {
      const int c = wid * 6 + j;         // 0..47
      const int tap = c >> 4, k = c & 15;
      const uint16_t* src =
          Wl + (size_t)(tap * 3 + g) * 32768 + oo * 64 + k * 512;
      gld16(src + lane * 8, as + tap * 8192 + k * 512);
    }
  };
  stage_a(0, 0);

  const int wm  = wid & 1;      // o sub-block (64 each)
  const int wn  = wid >> 1;     // h-row-pair index 0..3
  const int l15 = lane & 15;
  const int lg  = lane >> 4;    // k-group

  __syncthreads();              // x + A(ot0,g0) resident

  for (int ot = 0; ot < 4; ++ot) {
    const int o0 = ot * 128;
    f32x4 acc[8][4];
#pragma unroll
    for (int pb = 0; pb < 8; ++pb)
#pragma unroll
      for (int ob = 0; ob < 4; ++ob)
        acc[pb][ob] = (f32x4){0.f, 0.f, 0.f, 0.f};
    float bvv[4];
#pragma unroll
    for (int ob = 0; ob < 4; ++ob)
      bvv[ob] = bias[o0 + wm * 64 + ob * 16 + l15];

#pragma unroll
    for (int g = 0; g < 3; ++g) {
      const int dw = g - 1;
#pragma unroll
      for (int q = 0; q < 2; ++q) {
        const int cbB = (q * 4 + lg) ^ ((l15 + dw) & 7);
        const uint16_t* xb = xs + (l15 + dw + 1) * 64 + cbB * 8;
        const int cbA = (q * 4 + lg) ^ (l15 & 7);
        const uint16_t* ab = as + (wm * 64 + l15) * 64 + cbA * 8;
        bf16x8 braw[4][4];
#pragma unroll
        for (int dh = 0; dh < 3; ++dh) {
          // JIT B rows: dh0 -> rows 0,1 ; dh1 -> row 2 ; dh2 -> row 3
          if (dh == 0) {
#pragma unroll
            for (int r = 0; r < 2; ++r)
#pragma unroll
              for (int nw = 0; nw < 4; ++nw)
                braw[r][nw] = __builtin_bit_cast(bf16x8,
                    *reinterpret_cast<const s16x8*>(
                        xb + (wn * 2 + r) * 4224 + nw * 1024));
          } else {
            const int r = dh + 1;
#pragma unroll
            for (int nw = 0; nw < 4; ++nw)
              braw[r][nw] = __builtin_bit_cast(bf16x8,
                  *reinterpret_cast<const s16x8*>(
                      xb + (wn * 2 + r) * 4224 + nw * 1024));
          }
          bf16x8 af[4];
#pragma unroll
          for (int ob = 0; ob < 4; ++ob)
            af[ob] = __builtin_bit_cast(bf16x8,
                *reinterpret_cast<const s16x8*>(ab + dh * 8192 + ob * 1024));
          __builtin_amdgcn_s_setprio(1);
#pragma unroll
          for (int pb = 0; pb < 8; ++pb)
#pragma unroll
            for (int ob = 0; ob < 4; ++ob)
              acc[pb][ob] = __builtin_amdgcn_mfma_f32_16x16x32_bf16(
                  braw[(pb >> 2) + dh][pb & 3], af[ob], acc[pb][ob], 0, 0, 0);
          __builtin_amdgcn_s_setprio(0);
          __builtin_amdgcn_s_barrier();
        }
      }
      if (g < 2) {
        asm volatile("s_waitcnt lgkmcnt(0)" ::: "memory");
        __builtin_amdgcn_s_barrier();    // readers of as done (no vmcnt drain)
        stage_a(ot, g + 1);
        __syncthreads();                 // as(g+1) resident
      }
    }

    // ---- o-tile end: restage-first, stores after, counted wait ----
    asm volatile("s_waitcnt lgkmcnt(0)" ::: "memory");
    __builtin_amdgcn_s_barrier();        // all waves done reading as
    if (ot < 3) stage_a(ot + 1, 0);      // 6 gld16 (OLDER than stores)
    asm volatile("" ::: "memory");
    const int hb = h0 + wn * 2;
#pragma unroll
    for (int pb = 0; pb < 8; ++pb) {
#pragma unroll
      for (int ob = 0; ob < 4; ++ob) {
        const int o = o0 + wm * 64 + ob * 16 + l15;
        f32x4 v = acc[pb][ob];
        const float bv = bvv[ob];
        v[0] += bv; v[1] += bv; v[2] += bv; v[3] += bv;
        float* dst = out +
            ((size_t)(b * NO + o) * NH + hb + (pb >> 2)) * NW +
            (pb & 3) * 16 + lg * 4;
        __builtin_nontemporal_store(v, reinterpret_cast<f32x4*>(dst));
      }
    }
    if (ot < 3) {
      // 38 outstanding = 6 gld16 (old) + 32 stores (new); wait <=32 ->
      // exactly the gld16s. Stores drain under next o-tile's compute.
      asm volatile("s_waitcnt vmcnt(32)" ::: "memory");
      __builtin_amdgcn_s_barrier();      // as(ot+1,g0) resident block-wide
    }
  }
}

extern "C" void kernel_launch(void* const* d_in, const int* in_sizes, int n_in,
                              void* d_out, int out_size, void* d_ws, size_t ws_size,
                              hipStream_t stream) {
  const float* x    = (const float*)d_in[0];
  const float* dict = (const float*)d_in[1];
  const float* coef = (const float*)d_in[2];
  const float* bias = (const float*)d_in[3];
  const int*   idx  = (const int*)d_in[4];
  float* out = (float*)d_out;

  // workspace: xh padded/swizzled = 32*66*4096*2 B = 16.5 MiB at 0;
  //            Wl swizzled 576 KiB at +18 MiB
  uint16_t* xh = (uint16_t*)d_ws;
  uint16_t* Wl = (uint16_t*)((char*)d_ws + (18u << 20));

  hipLaunchKernelGGL(k_build_w, dim3(NO), dim3(576), 0, stream, dict, coef, idx, Wl);
  hipLaunchKernelGGL(k_nhwc, dim3(NB * HP), dim3(256), 0, stream, x, xh);
  hipLaunchKernelGGL(k_conv, dim3(256), dim3(512), 0, stream, xh, Wl, bias, out);
}

// Round 8
// 111.187 us; speedup vs baseline: 1.3375x; 1.3375x over previous
//
#include <hip/hip_runtime.h>
#include <stdint.h>

// Problem constants (fixed by reference)
#define NB 32    // batch
#define NC 64    // input channels
#define NH 64
#define NW 64
#define NO 512   // output channels
#define HP 66    // h-padded rows (1 zero row top+bottom)

typedef __bf16 bf16x8 __attribute__((ext_vector_type(8)));
typedef short  s16x8  __attribute__((ext_vector_type(8)));
typedef float  f32x4  __attribute__((ext_vector_type(4)));

__device__ __forceinline__ uint16_t f2bf(float f) {
  uint32_t u = __builtin_bit_cast(uint32_t, f);
  u += 0x7fffu + ((u >> 16) & 1u);   // round-to-nearest-even
  return (uint16_t)(u >> 16);
}

// async global->LDS, 16B per lane. LDS dest = wave-uniform base + lane*16.
__device__ __forceinline__ void gld16(const uint16_t* g, uint16_t* l) {
  __builtin_amdgcn_global_load_lds(
      (const __attribute__((address_space(1))) void*)(g),
      (__attribute__((address_space(3))) void*)(l), 16, 0, 0);
}

// ---------------- kernel 1: build effective weights (pre-swizzled) -------
// W_eff[o][c][p] = sum_s coef[o,s]*dict[idx[o,s]][c][p], p = kh*3+kw.
// Global layout matches the LDS tile EXACTLY (staging is a linear DMA):
//   Wl[((p*NO + o)*8 + ((c>>3) ^ (o&7)))*8 + (c&7)]
__global__ void k_build_w(const float* __restrict__ dict,
                          const float* __restrict__ coef,
                          const int*   __restrict__ idx,
                          uint16_t*    __restrict__ Wl) {
  __shared__ float tmp[576];
  const int o = blockIdx.x;
  const int t = threadIdx.x;      // 0..575
  float v = 0.f;
#pragma unroll
  for (int s = 0; s < 4; ++s)
    v += coef[o * 4 + s] * dict[idx[o * 4 + s] * 576 + t];
  tmp[t] = v;
  __syncthreads();
  const int c = t & 63, p = t >> 6;   // 576 = 9*64
  const int sl = ((p * NO + o) * 8 + ((c >> 3) ^ (o & 7))) * 8 + (c & 7);
  Wl[sl] = f2bf(tmp[c * 9 + p]);
}

// ---------------- kernel 2: x NCHW fp32 -> padded swizzled NHWC bf16 -----
// xh[b][hp][w][c] with hp in [0,66), rows 0 and 65 all-zero; within a row,
// 16B chunk (c>>3) stored at chunk position ((c>>3) ^ (w&7)).
__global__ void k_nhwc(const float* __restrict__ x, uint16_t* __restrict__ xh) {
  const int bh = blockIdx.x;            // b*66 + hp
  const int b = bh / HP, hp = bh % HP;
  const int t = threadIdx.x;            // 256
  uint16_t* row = xh + (size_t)(b * HP + hp) * 4096;
  if (hp == 0 || hp == HP - 1) {        // zero pad rows
    int4* r4 = reinterpret_cast<int4*>(row);
    r4[t]       = int4{0, 0, 0, 0};
    r4[t + 256] = int4{0, 0, 0, 0};
    return;
  }
  __shared__ float tile[64][65];
  const int h = hp - 1;
  const int w = t & 63;
#pragma unroll
  for (int c = (t >> 6); c < 64; c += 4)
    tile[c][w] = x[((size_t)(b * NC + c) * NH + h) * NW + w];
  __syncthreads();
#pragma unroll
  for (int i = 0; i < 2; ++i) {
    const int s = t + i * 256;          // 512 slots of 16B
    const int w2 = s >> 3, cb = s & 7;
    uint32_t d[4];
#pragma unroll
    for (int j = 0; j < 4; ++j) {
      const uint32_t lo = f2bf(tile[cb * 8 + 2 * j][w2]);
      const uint32_t hi = f2bf(tile[cb * 8 + 2 * j + 1][w2]);
      d[j] = lo | (hi << 16);
    }
    reinterpret_cast<int4*>(row)[w2 * 8 + (cb ^ (w2 & 7))] =
        int4{(int)d[0], (int)d[1], (int)d[2], (int)d[3]};
  }
}

// ---------------- kernel 3: BARRIER-FREE implicit-GEMM conv --------------
// 2048 blocks (8 rounds of 256), 512 thr (8 waves). Block = 64 o x 512 pix
// (8 h-rows of one b). Stage xs (10 halo'd rows, 84.5 KB) AND all 9 taps of
// the 64-o weight slice (72 KB) -> ONE __syncthreads -> per wave an
// unbarriered straight-line stream: 144 ds_read_b128 + 288 MFMA + 16 f32x4
// nt stores. Waves free-run; compiler interleaves reads/MFMA via lgkmcnt.
// Per wave: 64 pix (1 h-row) x 64 o, acc[4][4] (D rows = pixels via operand
// swap -> lane holds 4 consecutive w -> direct stores; layout verified R7).
__global__ __launch_bounds__(512, 2) void k_conv(
    const uint16_t* __restrict__ xh,   // [NB][66][64][64] bf16, pre-swizzled
    const uint16_t* __restrict__ Wl,   // [9][512][64] bf16, pre-swizzled
    const float*    __restrict__ bias,
    float*          __restrict__ out) {
  __shared__ __align__(16) uint16_t xs[10 * 66 * 64];     // 84,480 B
  __shared__ __align__(16) uint16_t as[9 * 64 * 64];      // 73,728 B

  const int t = threadIdx.x;
  // XCD-chunked: XCD k gets gy in [k*32,(k+1)*32) (4 b's, L2-resident)
  const int flat = blockIdx.x;                 // 2048 blocks
  const int s    = (flat & 7) * 256 + (flat >> 3);
  const int ot   = s & 7;                      // o-tile (8 x 64)
  const int gy   = s >> 3;                     // pixel tile: b*8 + h-octet
  const int o0 = ot * 64;
  const int b  = gy >> 3;
  const int h0 = (gy & 7) * 8;

  const int lane = t & 63;
  const int wid  = t >> 6;      // 0..7

  // ---- zero the w-halo slots (slot 0 and 65 of each of 10 rows) ----
  if (t < 160) {
    const int r = t >> 4, sl = (t >> 3) & 1, j = t & 7;
    reinterpret_cast<int4*>(xs)[r * 528 + sl * 520 + j] = int4{0, 0, 0, 0};
  }

  // ---- stage x interior: rows 0..7 -> wave wid; rows 8,9 split ----
  {
    const uint16_t* srow = xh + (size_t)(b * HP + h0 + wid) * 4096;
    uint16_t* drow = xs + wid * 4224 + 64;     // skip w-halo slot 0
#pragma unroll
    for (int k = 0; k < 8; ++k)
      gld16(srow + k * 512 + lane * 8, drow + k * 512);
    const int r2 = 8 + (wid >> 2);
    const int kb = (wid & 3) * 2;
    const uint16_t* srow2 = xh + (size_t)(b * HP + h0 + r2) * 4096;
    uint16_t* drow2 = xs + r2 * 4224 + 64;
    gld16(srow2 + kb * 512 + lane * 8, drow2 + kb * 512);
    gld16(srow2 + (kb + 1) * 512 + lane * 8, drow2 + (kb + 1) * 512);
  }

  // ---- stage ALL 9 taps of the 64-o weight slice: 72 x 1 KB chunks ----
  // tap p occupies 8 chunks (64 o x 64 c x 2 B). wave wid takes 9 chunks.
  {
#pragma unroll
    for (int j = 0; j < 9; ++j) {
      const int c = wid * 9 + j;         // 0..71
      const int tap = c >> 3, k = c & 7;
      const uint16_t* src =
          Wl + (size_t)tap * 32768 + o0 * 64 + k * 512;
      gld16(src + lane * 8, as + tap * 4096 + k * 512);
    }
  }

  const int wn  = wid;          // h-row within octet (wave owns 1 row)
  const int l15 = lane & 15;
  const int lg  = lane >> 4;    // k-group

  f32x4 acc[4][4];
#pragma unroll
  for (int pb = 0; pb < 4; ++pb)
#pragma unroll
    for (int ob = 0; ob < 4; ++ob)
      acc[pb][ob] = (f32x4){0.f, 0.f, 0.f, 0.f};
  float bvv[4];
#pragma unroll
  for (int ob = 0; ob < 4; ++ob)
    bvv[ob] = bias[o0 + ob * 16 + l15];

  __syncthreads();              // xs + as resident (vmcnt+lgkm drained)

  // ---- the whole conv: 6 (g,q) regions, ZERO barriers ----
#pragma unroll
  for (int g = 0; g < 3; ++g) {
    const int dw = g - 1;
#pragma unroll
    for (int q = 0; q < 2; ++q) {
      const int cbB = (q * 4 + lg) ^ ((l15 + dw) & 7);
      const uint16_t* xb = xs + (l15 + dw + 1) * 64 + cbB * 8;
      const int cbA = (q * 4 + lg) ^ (l15 & 7);
      const uint16_t* ab = as + l15 * 64 + cbA * 8;
#pragma unroll
      for (int dh = 0; dh < 3; ++dh) {
        const int tap = dh * 3 + g;
        bf16x8 braw[4], af[4];
#pragma unroll
        for (int nw = 0; nw < 4; ++nw)
          braw[nw] = __builtin_bit_cast(bf16x8,
              *reinterpret_cast<const s16x8*>(
                  xb + (wn + dh) * 4224 + nw * 1024));
#pragma unroll
        for (int ob = 0; ob < 4; ++ob)
          af[ob] = __builtin_bit_cast(bf16x8,
              *reinterpret_cast<const s16x8*>(
                  ab + tap * 4096 + ob * 1024));
#pragma unroll
        for (int pb = 0; pb < 4; ++pb)
#pragma unroll
          for (int ob = 0; ob < 4; ++ob)
            acc[pb][ob] = __builtin_amdgcn_mfma_f32_16x16x32_bf16(
                braw[pb], af[ob], acc[pb][ob], 0, 0, 0);
      }
    }
  }

  // ---- epilogue: direct f32x4 nt stores (layout verified R7) ----
  const int h = h0 + wn;
#pragma unroll
  for (int pb = 0; pb < 4; ++pb) {
#pragma unroll
    for (int ob = 0; ob < 4; ++ob) {
      const int o = o0 + ob * 16 + l15;
      f32x4 v = acc[pb][ob];
      const float bv = bvv[ob];
      v[0] += bv; v[1] += bv; v[2] += bv; v[3] += bv;
      float* dst = out + ((size_t)(b * NO + o) * NH + h) * NW +
                   pb * 16 + lg * 4;
      __builtin_nontemporal_store(v, reinterpret_cast<f32x4*>(dst));
    }
  }
}

extern "C" void kernel_launch(void* const* d_in, const int* in_sizes, int n_in,
                              void* d_out, int out_size, void* d_ws, size_t ws_size,
                              hipStream_t stream) {
  const float* x    = (const float*)d_in[0];
  const float* dict = (const float*)d_in[1];
  const float* coef = (const float*)d_in[2];
  const float* bias = (const float*)d_in[3];
  const int*   idx  = (const int*)d_in[4];
  float* out = (float*)d_out;

  // workspace: xh padded/swizzled = 32*66*4096*2 B = 16.5 MiB at 0;
  //            Wl swizzled 576 KiB at +18 MiB
  uint16_t* xh = (uint16_t*)d_ws;
  uint16_t* Wl = (uint16_t*)((char*)d_ws + (18u << 20));

  hipLaunchKernelGGL(k_build_w, dim3(NO), dim3(576), 0, stream, dict, coef, idx, Wl);
  hipLaunchKernelGGL(k_nhwc, dim3(NB * HP), dim3(256), 0, stream, x, xh);
  hipLaunchKernelGGL(k_conv, dim3(2048), dim3(512), 0, stream, xh, Wl, bias, out);
}